// Round 2
// baseline (48.707 us; speedup 1.0000x reference)
//
#include <hip/hip_runtime.h>
#include <hip/hip_bf16.h>

// SCC: out[b,o,h,w] = sum_{j=0..7} w[o,j] * x[b, (o*4 + j) % 64, h, w]
// B=32, C_IN=C_OUT=64, H=W=128, G=8, STEP=4. All float32.
//
// Key structure: outputs {o, o+16, o+32, o+48} share the same 8-channel
// input window (4*(o+16) == 4*o mod 64). So slide a window over 16 base
// positions; at each position load 4 new channels and emit 4 outputs.
// Each thread processes 4 consecutive pixels as float4 (16 B/lane loads
// and stores). Only 8 channels x float4 = 32 VGPRs of x live at a time.

#define CIN   64
#define COUT  64
#define GW    8
#define STEP  4
#define HW4   4096            // (128*128)/4 float4-pixels per channel plane

__global__ __launch_bounds__(256) void scc_kernel(
    const float4* __restrict__ x,
    const float*  __restrict__ w,
    float4* __restrict__ out)
{
    __shared__ float4 wsv[COUT * 2];          // 512 floats, float4-aliased
    {
        float* ws = (float*)wsv;
        for (int i = threadIdx.x; i < COUT * GW; i += blockDim.x)
            ws[i] = w[i];
    }
    __syncthreads();

    int t   = blockIdx.x * blockDim.x + threadIdx.x;  // float4-pixel id
    int b   = t >> 12;                                // / 4096
    int hw4 = t & (HW4 - 1);

    const float4* xp = x   + ((long)b * CIN) * HW4 + hw4;
    float4*       op = out + ((long)b * COUT) * HW4 + hw4;

    // Prime the window with channels 0..7.
    float4 win[8];
#pragma unroll
    for (int k = 0; k < 8; ++k)
        win[k] = xp[(long)k * HW4];

#pragma unroll
    for (int wi = 0; wi < 16; ++wi) {
        // Prefetch the next 4 channels (window slides by STEP=4).
        float4 nxt[4];
        if (wi < 15) {
#pragma unroll
            for (int k = 0; k < 4; ++k) {
                int c = (4 * wi + 8 + k) & (CIN - 1);
                nxt[k] = xp[(long)c * HW4];
            }
        }

        // 4 outputs share this window: o = wi + 16*q.
#pragma unroll
        for (int q = 0; q < 4; ++q) {
            int o = wi + 16 * q;
            float4 w0 = wsv[o * 2 + 0];
            float4 w1 = wsv[o * 2 + 1];
            float4 a;
            a.x = 0.f; a.y = 0.f; a.z = 0.f; a.w = 0.f;
#pragma unroll
            for (int j = 0; j < 8; ++j) {
                float wt = (j < 4) ? ((const float*)&w0)[j]
                                   : ((const float*)&w1)[j - 4];
                float4 xv = win[(4 * wi + j) & 7];
                a.x = fmaf(wt, xv.x, a.x);
                a.y = fmaf(wt, xv.y, a.y);
                a.z = fmaf(wt, xv.z, a.z);
                a.w = fmaf(wt, xv.w, a.w);
            }
            op[(long)o * HW4] = a;
        }

        // Rotate prefetched channels into the window (static indices).
        if (wi < 15) {
#pragma unroll
            for (int k = 0; k < 4; ++k)
                win[(4 * wi + 8 + k) & 7] = nxt[k];
        }
    }
}

extern "C" void kernel_launch(void* const* d_in, const int* in_sizes, int n_in,
                              void* d_out, int out_size, void* d_ws, size_t ws_size,
                              hipStream_t stream) {
    const float4* x = (const float4*)d_in[0];
    const float*  w = (const float*)d_in[1];
    float4* out     = (float4*)d_out;

    const int total_vec = 32 * HW4;           // 131072 float4-pixels
    const int block = 256;
    const int grid  = total_vec / block;      // 512

    scc_kernel<<<grid, block, 0, stream>>>(x, w, out);
}